// Round 1
// baseline (6341.593 us; speedup 1.0000x reference)
//
#include <hip/hip_runtime.h>
#include <hip/hip_bf16.h>
#include <math.h>

// ---------------- constants (fixed by setup_inputs) ----------------
constexpr int B   = 128;   // batch
constexpr int T   = 22;    // input time steps
constexpr int N1  = 32;    // agents (1 ego + 31 veh)
constexpr int HH  = 20;    // history steps (T-2)
constexpr int L   = 64;    // lanes
constexpr int PTS = 10;    // points per lane
constexpr int F   = 128;   // feature size
constexpr int LF  = 64;    // lane feature
constexpr int NH  = 8;     // heads
constexpr int HD  = 16;    // head dim
constexpr int KVN = 96;    // kv tokens = 32 agents + 64 lanes
constexpr int G4  = 512;   // 4*F lstm gates
constexpr int NP  = 6;     // num preds
constexpr int P6  = 36;    // NP*6
constexpr int LEN = 30;    // len_pred

__device__ __forceinline__ float sigmoidf(float x) { return 1.f / (1.f + expf(-x)); }

// ---------------- one-time kernels ----------------

// lane MLP -> lane tokens, written into kvbuf rows 32..95 of each batch
__global__ void k_lane_tok(const float* __restrict__ lane_input,
                           const float* __restrict__ w1, const float* __restrict__ b1,
                           const float* __restrict__ w2, const float* __restrict__ b2,
                           const float* __restrict__ to_f,
                           float* __restrict__ kvbuf) {
    int bl = blockIdx.x; int b = bl / L, l = bl % L;
    int tid = threadIdx.x; // 64 threads
    __shared__ float h1[PTS][LF];
    __shared__ float m[LF];
    const float* xin = lane_input + ((size_t)(b * L + l) * PTS) * 2;
    float w10 = w1[tid], w11 = w1[LF + tid], bb1 = b1[tid];
    for (int p = 0; p < PTS; ++p) {
        float v = xin[p * 2] * w10 + xin[p * 2 + 1] * w11 + bb1;
        h1[p][tid] = fmaxf(v, 0.f);
    }
    __syncthreads();
    float acc = 0.f;
    for (int p = 0; p < PTS; ++p) {
        float s = b2[tid];
        for (int h = 0; h < LF; ++h) s += h1[p][h] * w2[h * LF + tid];
        acc += fmaxf(s, 0.f);
    }
    m[tid] = acc * (1.f / PTS);
    __syncthreads();
    float* out = kvbuf + ((size_t)(b * KVN) + 32 + l) * F;
    for (int f = tid; f < F; f += LF) {
        float s = 0.f;
        for (int j = 0; j < LF; ++j) s += m[j] * to_f[j * F + f];
        out[f] = s;
    }
}

// cumulative positions over history: hist_pos[t] = init + sum_{tau<=t} to_xy(input[tau])
__global__ void k_hist_pos(const float* __restrict__ input,
                           const float* __restrict__ init_pos,
                           float* __restrict__ hist_pos) {
    int idx = blockIdx.x * blockDim.x + threadIdx.x;
    if (idx >= B * N1) return;
    float px = init_pos[idx * 2], py = init_pos[idx * 2 + 1];
    int b = idx / N1, n = idx % N1;
    for (int t = 0; t < HH; ++t) {
        const float* ip = input + ((size_t)(t * B + b) * N1 + n) * 2;
        float dl = ip[0], yaw = ip[1];
        px += dl * cosf(yaw);
        py += dl * sinf(yaw);
        float* hp = hist_pos + ((size_t)(t * B + b) * N1 + n) * 2;
        hp[0] = px; hp[1] = py;
    }
}

// transpose (G4,F) row-major -> (F,G4) for coalesced gate matmul reads
__global__ void k_transpose_w(const float* __restrict__ w, float* __restrict__ wt) {
    int i = blockIdx.x * blockDim.x + threadIdx.x;
    if (i >= G4 * F) return;
    int j = i / F, k2 = i % F;
    wt[k2 * G4 + j] = w[i];
}

// pred positions init: replicate hist_pos[HH-1] over NP preds
__global__ void k_init_predpos(const float* __restrict__ hist_pos, float* __restrict__ pred_pos) {
    int i = blockIdx.x * blockDim.x + threadIdx.x;
    if (i >= B * N1 * NP * 2) return;
    int c = i & 1;
    int bn = i / (2 * NP);
    pred_pos[i] = hist_pos[((size_t)(HH - 1) * B * N1 + bn) * 2 + c];
}

// ---------------- per-step kernels ----------------

// history token: conv feature + positional embedding -> kvbuf rows 0..31
__global__ void k_tok_hist(const float* __restrict__ input,
                           const float* __restrict__ conv_w, const float* __restrict__ conv_b,
                           const float* __restrict__ pos_w, const float* __restrict__ pos_b,
                           const float* __restrict__ hist_pos,
                           float* __restrict__ kvbuf, int t) {
    int bn = blockIdx.x; int b = bn / N1, n = bn % N1;
    int f = threadIdx.x;
    float acc = conv_b[f];
#pragma unroll
    for (int kt = 0; kt < 3; ++kt) {
        const float* ip = input + ((size_t)((t + kt) * B + b) * N1 + n) * 2;
        acc += ip[0] * conv_w[(f * 2 + 0) * 3 + kt] + ip[1] * conv_w[(f * 2 + 1) * 3 + kt];
    }
    const float* hp = hist_pos + ((size_t)(t * B + b) * N1 + n) * 2;
    acc += hp[0] * pos_w[f] + hp[1] * pos_w[F + f] + pos_b[f];
    kvbuf[((size_t)b * KVN + n) * F + f] = acc;
}

// pred token: h state + positional embedding of mean pred pos -> kvbuf rows 0..31
__global__ void k_tok_pred(const float* __restrict__ h, const float* __restrict__ pred_pos,
                           const float* __restrict__ pos_w, const float* __restrict__ pos_b,
                           float* __restrict__ kvbuf) {
    int bn = blockIdx.x; int b = bn / N1, n = bn % N1;
    int f = threadIdx.x;
    const float* pp = pred_pos + (size_t)bn * NP * 2;
    float mx = 0.f, my = 0.f;
#pragma unroll
    for (int p = 0; p < NP; ++p) { mx += pp[p * 2]; my += pp[p * 2 + 1]; }
    mx *= (1.f / NP); my *= (1.f / NP);
    float tok = h[(size_t)bn * F + f] + mx * pos_w[f] + my * pos_w[F + f] + pos_b[f];
    kvbuf[((size_t)b * KVN + n) * F + f] = tok;
}

// q,k,v projections: 8 rows per block. 28 groups/batch: 4 q-groups, 12 k, 12 v
__global__ void k_qkv(const float* __restrict__ kvbuf,
                      const float* __restrict__ wq, const float* __restrict__ wk,
                      const float* __restrict__ wv,
                      float* __restrict__ qbuf, float* __restrict__ kbuf,
                      float* __restrict__ vbuf) {
    int g = blockIdx.x % 28, b = blockIdx.x / 28;
    int j = threadIdx.x; // 128
    const float* W; float* out; int row0;
    if (g < 4)       { W = wq; row0 = g * 8;        out = qbuf + ((size_t)b * N1  + row0) * F; }
    else if (g < 16) { W = wk; row0 = (g - 4) * 8;  out = kbuf + ((size_t)b * KVN + row0) * F; }
    else             { W = wv; row0 = (g - 16) * 8; out = vbuf + ((size_t)b * KVN + row0) * F; }
    const float* in = kvbuf + ((size_t)b * KVN + row0) * F;
    __shared__ float rows[8][F];
#pragma unroll
    for (int r = 0; r < 8; ++r) rows[r][j] = in[r * F + j];
    __syncthreads();
    float acc[8] = {0, 0, 0, 0, 0, 0, 0, 0};
    for (int k2 = 0; k2 < F; ++k2) {
        float w = W[k2 * F + j];
#pragma unroll
        for (int r = 0; r < 8; ++r) acc[r] += rows[r][k2] * w;
    }
#pragma unroll
    for (int r = 0; r < 8; ++r) out[r * F + j] = acc[r];
}

// per-(batch,head) attention: scores, masked softmax, value aggregation
__global__ void k_attn(const float* __restrict__ qbuf, const float* __restrict__ kbuf,
                       const float* __restrict__ vbuf,
                       const float* __restrict__ mask_in, const float* __restrict__ lane_mask,
                       float* __restrict__ attno) {
    int h = blockIdx.x % NH, b = blockIdx.x / NH;
    int tid = threadIdx.x; // 128
    __shared__ float qs[N1][HD];
    __shared__ float s[N1][KVN];
    for (int i = tid; i < N1 * HD; i += 128) {
        int qr = i / HD, d = i % HD;
        qs[qr][d] = qbuf[((size_t)b * N1 + qr) * F + h * HD + d];
    }
    __syncthreads();
    for (int i = tid; i < N1 * KVN; i += 128) {
        int qr = i / KVN, kc = i % KVN;
        const float* kp = kbuf + ((size_t)b * KVN + kc) * F + h * HD;
        float acc = 0.f;
#pragma unroll
        for (int d = 0; d < HD; ++d) acc += qs[qr][d] * kp[d];
        float mval = (kc < N1) ? mask_in[b * N1 + kc] : lane_mask[b * L + (kc - N1)];
        s[qr][kc] = (mval > 0.f) ? acc * 0.25f : -1e9f;
    }
    __syncthreads();
    if (tid < N1) {
        float mx = -1e30f;
        for (int kc = 0; kc < KVN; ++kc) mx = fmaxf(mx, s[tid][kc]);
        float sum = 0.f;
        for (int kc = 0; kc < KVN; ++kc) { float e = expf(s[tid][kc] - mx); s[tid][kc] = e; sum += e; }
        float inv = 1.f / sum;
        for (int kc = 0; kc < KVN; ++kc) s[tid][kc] *= inv;
    }
    __syncthreads();
    for (int i = tid; i < N1 * HD; i += 128) {
        int qr = i / HD, d = i % HD;
        float acc = 0.f;
        for (int kc = 0; kc < KVN; ++kc)
            acc += s[qr][kc] * vbuf[((size_t)b * KVN + kc) * F + h * HD + d];
        attno[((size_t)b * N1 + qr) * F + h * HD + d] = acc;
    }
}

// output projection + residual + layernorm -> LSTM input. 4 rows per block.
__global__ void k_proj_ln(const float* __restrict__ attno, const float* __restrict__ kvbuf,
                          const float* __restrict__ wo,
                          const float* __restrict__ ln_ego_g, const float* __restrict__ ln_ego_b,
                          const float* __restrict__ ln_g, const float* __restrict__ ln_b,
                          float* __restrict__ xln) {
    int gi = blockIdx.x; int b = gi / 8, n0 = (gi % 8) * 4;
    int j = threadIdx.x; // 128
    __shared__ float arows[4][F];
    __shared__ float p1[2], p2[2];
#pragma unroll
    for (int r = 0; r < 4; ++r) arows[r][j] = attno[((size_t)b * N1 + n0 + r) * F + j];
    __syncthreads();
    float acc[4] = {0, 0, 0, 0};
    for (int k2 = 0; k2 < F; ++k2) {
        float w = wo[k2 * F + j];
#pragma unroll
        for (int r = 0; r < 4; ++r) acc[r] += arows[r][k2] * w;
    }
    for (int r = 0; r < 4; ++r) {
        int n = n0 + r;
        float x = kvbuf[((size_t)b * KVN + n) * F + j] + acc[r];
        float s1 = x, s2 = x * x;
#pragma unroll
        for (int off = 32; off > 0; off >>= 1) {
            s1 += __shfl_down(s1, off, 64);
            s2 += __shfl_down(s2, off, 64);
        }
        if ((j & 63) == 0) { p1[j >> 6] = s1; p2[j >> 6] = s2; }
        __syncthreads();
        float mean = (p1[0] + p1[1]) * (1.f / F);
        float var  = (p2[0] + p2[1]) * (1.f / F) - mean * mean;
        float rstd = rsqrtf(var + 1e-5f);
        const float* g  = (n == 0) ? ln_ego_g : ln_g;
        const float* bb = (n == 0) ? ln_ego_b : ln_b;
        xln[((size_t)b * N1 + n) * F + j] = (x - mean) * rstd * g[j] + bb[j];
        __syncthreads();
    }
}

// LSTM cell: 8 batches per block (fixed agent n -> fixed weight set)
__global__ void k_lstm(const float* __restrict__ xln,
                       const float* __restrict__ ego_wih_t, const float* __restrict__ ego_whh_t,
                       const float* __restrict__ ego_bih, const float* __restrict__ ego_bhh,
                       const float* __restrict__ veh_wih_t, const float* __restrict__ veh_whh_t,
                       const float* __restrict__ veh_bih, const float* __restrict__ veh_bhh,
                       float* __restrict__ h, float* __restrict__ c) {
    int n = blockIdx.x / 16; int b0 = (blockIdx.x % 16) * 8;
    int j = threadIdx.x; // 512
    const float *wih, *whh, *bih, *bhh;
    if (n == 0) { wih = ego_wih_t; whh = ego_whh_t; bih = ego_bih; bhh = ego_bhh; }
    else        { wih = veh_wih_t; whh = veh_whh_t; bih = veh_bih; bhh = veh_bhh; }
    __shared__ float xr[8][F], hr[8][F];
    __shared__ float gs[8][G4];
    for (int i = j; i < 8 * F; i += 512) {
        int r = i / F, k2 = i % F;
        size_t bn = (size_t)(b0 + r) * N1 + n;
        xr[r][k2] = xln[bn * F + k2];
        hr[r][k2] = h[bn * F + k2];
    }
    __syncthreads();
    float acc[8];
    float bsum = bih[j] + bhh[j];
#pragma unroll
    for (int r = 0; r < 8; ++r) acc[r] = bsum;
    for (int k2 = 0; k2 < F; ++k2) {
        float w1 = wih[k2 * G4 + j];
        float w2 = whh[k2 * G4 + j];
#pragma unroll
        for (int r = 0; r < 8; ++r) acc[r] += xr[r][k2] * w1 + hr[r][k2] * w2;
    }
#pragma unroll
    for (int r = 0; r < 8; ++r) gs[r][j] = acc[r];
    __syncthreads();
    for (int i = j; i < 8 * F; i += 512) {
        int r = i / F, f = i % F;
        size_t bn = (size_t)(b0 + r) * N1 + n;
        float ig = gs[r][f], fg = gs[r][F + f], gg = gs[r][2 * F + f], og = gs[r][3 * F + f];
        float cold = c[bn * F + f];
        float c2 = sigmoidf(fg) * cold + sigmoidf(ig) * tanhf(gg);
        float h2 = sigmoidf(og) * tanhf(c2);
        c[bn * F + f] = c2;
        h[bn * F + f] = h2;
    }
}

// prediction head: 36-dim output proj, position update, write y
__global__ void k_pred_out(const float* __restrict__ h,
                           const float* __restrict__ out_ego_w, const float* __restrict__ out_ego_b,
                           const float* __restrict__ out_w, const float* __restrict__ out_b,
                           float* __restrict__ pred_pos, float* __restrict__ out, int step) {
    int bn = blockIdx.x; int n = bn % N1;
    int j = threadIdx.x; // 64
    __shared__ float hrow[F];
    __shared__ float o36[P6];
    hrow[j] = h[(size_t)bn * F + j];
    hrow[j + 64] = h[(size_t)bn * F + j + 64];
    __syncthreads();
    const float* W  = (n == 0) ? out_ego_w : out_w;
    const float* bb = (n == 0) ? out_ego_b : out_b;
    if (j < P6) {
        float acc = bb[j];
        for (int k2 = 0; k2 < F; ++k2) acc += hrow[k2] * W[k2 * P6 + j];
        o36[j] = acc;
    }
    __syncthreads();
    if (j < NP) {
        float dl = o36[j * 6], yaw = o36[j * 6 + 1];
        float* pp = pred_pos + ((size_t)bn * NP + j) * 2;
        float px = pp[0] + dl * cosf(yaw);
        float py = pp[1] + dl * sinf(yaw);
        pp[0] = px; pp[1] = py;
        float* y = out + (size_t)step * B * N1 * P6 + ((size_t)bn * NP + j) * 6;
        y[0] = px; y[1] = py;
        y[2] = o36[j * 6 + 2]; y[3] = o36[j * 6 + 3];
        y[4] = o36[j * 6 + 4]; y[5] = o36[j * 6 + 5];
    }
}

// ---------------- launcher ----------------
extern "C" void kernel_launch(void* const* d_in, const int* in_sizes, int n_in,
                              void* d_out, int out_size, void* d_ws, size_t ws_size,
                              hipStream_t stream) {
    const float* input      = (const float*)d_in[0];
    const float* init_pos   = (const float*)d_in[1];
    const float* lane_input = (const float*)d_in[2];
    const float* mask_input = (const float*)d_in[3];
    const float* lane_mask  = (const float*)d_in[4];
    const float* conv_w     = (const float*)d_in[5];
    const float* conv_b     = (const float*)d_in[6];
    const float* pos_w      = (const float*)d_in[7];
    const float* pos_b      = (const float*)d_in[8];
    const float* lane_w1    = (const float*)d_in[9];
    const float* lane_b1    = (const float*)d_in[10];
    const float* lane_w2    = (const float*)d_in[11];
    const float* lane_b2    = (const float*)d_in[12];
    const float* lane_to_f  = (const float*)d_in[13];
    const float* wq         = (const float*)d_in[14];
    const float* wk         = (const float*)d_in[15];
    const float* wv         = (const float*)d_in[16];
    const float* wo         = (const float*)d_in[17];
    const float* ln_ego_g   = (const float*)d_in[18];
    const float* ln_ego_b   = (const float*)d_in[19];
    const float* ln_g       = (const float*)d_in[20];
    const float* ln_b       = (const float*)d_in[21];
    const float* ego_wih    = (const float*)d_in[22];
    const float* ego_whh    = (const float*)d_in[23];
    const float* ego_bih    = (const float*)d_in[24];
    const float* ego_bhh    = (const float*)d_in[25];
    const float* veh_wih    = (const float*)d_in[26];
    const float* veh_whh    = (const float*)d_in[27];
    const float* veh_bih    = (const float*)d_in[28];
    const float* veh_bhh    = (const float*)d_in[29];
    const float* out_ego_w  = (const float*)d_in[30];
    const float* out_ego_b  = (const float*)d_in[31];
    const float* out_w      = (const float*)d_in[32];
    const float* out_b      = (const float*)d_in[33];
    // d_in[34] = len_pred (scalar, fixed at 30 by setup_inputs)

    float* out = (float*)d_out;
    float* ws = (float*)d_ws;

    // workspace layout (floats)
    float* kv       = ws;                       // B*KVN*F
    float* qb       = kv + (size_t)B * KVN * F; // B*N1*F
    float* kb       = qb + (size_t)B * N1 * F;  // B*KVN*F
    float* vb       = kb + (size_t)B * KVN * F; // B*KVN*F
    float* attno    = vb + (size_t)B * KVN * F; // B*N1*F
    float* xln      = attno + (size_t)B * N1 * F;
    float* hbuf     = xln + (size_t)B * N1 * F;
    float* cbuf     = hbuf + (size_t)B * N1 * F;
    float* hist_pos = cbuf + (size_t)B * N1 * F;            // HH*B*N1*2
    float* pred_pos = hist_pos + (size_t)HH * B * N1 * 2;   // B*N1*NP*2
    float* wt       = pred_pos + (size_t)B * N1 * NP * 2;   // 4 * G4*F
    float* ego_wih_t = wt;
    float* ego_whh_t = wt + (size_t)G4 * F;
    float* veh_wih_t = wt + (size_t)2 * G4 * F;
    float* veh_whh_t = wt + (size_t)3 * G4 * F;

    // ---- init ----
    hipMemsetAsync(hbuf, 0, (size_t)B * N1 * F * sizeof(float), stream);
    hipMemsetAsync(cbuf, 0, (size_t)B * N1 * F * sizeof(float), stream);
    k_lane_tok<<<B * L, 64, 0, stream>>>(lane_input, lane_w1, lane_b1, lane_w2, lane_b2,
                                         lane_to_f, kv);
    k_hist_pos<<<(B * N1 + 255) / 256, 256, 0, stream>>>(input, init_pos, hist_pos);
    k_transpose_w<<<(G4 * F + 255) / 256, 256, 0, stream>>>(ego_wih, ego_wih_t);
    k_transpose_w<<<(G4 * F + 255) / 256, 256, 0, stream>>>(ego_whh, ego_whh_t);
    k_transpose_w<<<(G4 * F + 255) / 256, 256, 0, stream>>>(veh_wih, veh_wih_t);
    k_transpose_w<<<(G4 * F + 255) / 256, 256, 0, stream>>>(veh_whh, veh_whh_t);

    // ---- history ----
    for (int t = 0; t < HH; ++t) {
        k_tok_hist<<<B * N1, F, 0, stream>>>(input, conv_w, conv_b, pos_w, pos_b,
                                             hist_pos, kv, t);
        k_qkv<<<B * 28, F, 0, stream>>>(kv, wq, wk, wv, qb, kb, vb);
        k_attn<<<B * NH, 128, 0, stream>>>(qb, kb, vb, mask_input, lane_mask, attno);
        k_proj_ln<<<B * 8, 128, 0, stream>>>(attno, kv, wo, ln_ego_g, ln_ego_b, ln_g, ln_b, xln);
        k_lstm<<<N1 * 16, G4, 0, stream>>>(xln, ego_wih_t, ego_whh_t, ego_bih, ego_bhh,
                                           veh_wih_t, veh_whh_t, veh_bih, veh_bhh, hbuf, cbuf);
    }

    k_init_predpos<<<(B * N1 * NP * 2 + 255) / 256, 256, 0, stream>>>(hist_pos, pred_pos);

    // ---- prediction ----
    for (int s = 0; s < LEN; ++s) {
        k_tok_pred<<<B * N1, F, 0, stream>>>(hbuf, pred_pos, pos_w, pos_b, kv);
        k_qkv<<<B * 28, F, 0, stream>>>(kv, wq, wk, wv, qb, kb, vb);
        k_attn<<<B * NH, 128, 0, stream>>>(qb, kb, vb, mask_input, lane_mask, attno);
        k_proj_ln<<<B * 8, 128, 0, stream>>>(attno, kv, wo, ln_ego_g, ln_ego_b, ln_g, ln_b, xln);
        k_lstm<<<N1 * 16, G4, 0, stream>>>(xln, ego_wih_t, ego_whh_t, ego_bih, ego_bhh,
                                           veh_wih_t, veh_whh_t, veh_bih, veh_bhh, hbuf, cbuf);
        k_pred_out<<<B * N1, 64, 0, stream>>>(hbuf, out_ego_w, out_ego_b, out_w, out_b,
                                              pred_pos, out, s);
    }
}